// Round 3
// baseline (179509.314 us; speedup 1.0000x reference)
//
#include <hip/hip_runtime.h>

typedef unsigned int u32;
typedef unsigned short u16;
#define DEV __device__ __forceinline__

// ---------------- problem sizes ----------------
#define T_DEC 300
#define NB    16
#define T_ENC 200
#define EDIM  512
#define ARNN  1024
#define PDIM  256
#define ADIM  128
#define NMEL  80

// ---------------- ws layout ----------------
// ints [0..4095]: barrier flags (stride 16); [4095] = dtype flag (blocks use 0..4080)
#define OFF_ATT_H   4096                     // 2 * 16*1024 f32
#define OFF_DEC_H   (OFF_ATT_H + 2*NB*ARNN)
#define OFF_CTX     (OFF_DEC_H + 2*NB*ARNN)  // 2 * 16*512
#define OFF_PRENET  (OFF_CTX + 2*NB*EDIM)    // 2 * 16*256
#define OFF_F32_END (OFF_PRENET + 2*NB*PDIM) // 94208 f32 = 376832 B
#define NEED_STATE  (OFF_F32_END * 4)
#define NEED_PM     (NEED_STATE + NB*ADIM*T_ENC*2)   // + 819200 B (pm bf16)

// ---------------- out layout (elements) ----------------
#define OUT_GATE  (NB*NMEL*T_DEC)        // 384000
#define OUT_ALIGN (OUT_GATE + NB*T_DEC)  // 388800

// ---------------- helpers ----------------
DEV float bflo(u32 u){ return __uint_as_float(u << 16); }
DEV float bfhi(u32 u){ return __uint_as_float(u & 0xffff0000u); }
DEV float bf2f(u16 h){ return __uint_as_float(((u32)h) << 16); }
DEV u16 f2bf(float f){
  u32 u = __float_as_uint(f);
  u32 r = (u + 0x7fffu + ((u >> 16) & 1u)) >> 16;
  return (u16)r;
}
DEV float fsig(float x){ return 1.0f / (1.0f + __expf(-x)); }
DEV float ftanh(float x){
  float xx = fminf(15.0f, fmaxf(-15.0f, x));
  float e = __expf(2.0f * xx);
  return (e - 1.0f) / (e + 1.0f);
}

// adaptive scalar load / store (bf = inputs are bf16, else fp32)
DEV float ldv(const void* p, size_t i, bool bf){
  return bf ? bf2f(((const u16*)p)[i]) : ((const float*)p)[i];
}
DEV void stv(void* o, size_t i, float v, bool bf){
  if (bf) ((u16*)o)[i] = f2bf(v);
  else    ((float*)o)[i] = v;
}

// 16-element weight x f32 dot, adaptive dtype; base must be 16-elem aligned
DEV float dot16a(const void* w, size_t base, const float* __restrict__ xr, bool bf){
  float s = 0.f;
  if (bf){
    const uint4* p = (const uint4*)((const u16*)w + base);
    uint4 a = p[0], b = p[1];
    s = fmaf(bflo(a.x), xr[0],  s); s = fmaf(bfhi(a.x), xr[1],  s);
    s = fmaf(bflo(a.y), xr[2],  s); s = fmaf(bfhi(a.y), xr[3],  s);
    s = fmaf(bflo(a.z), xr[4],  s); s = fmaf(bfhi(a.z), xr[5],  s);
    s = fmaf(bflo(a.w), xr[6],  s); s = fmaf(bfhi(a.w), xr[7],  s);
    s = fmaf(bflo(b.x), xr[8],  s); s = fmaf(bfhi(b.x), xr[9],  s);
    s = fmaf(bflo(b.y), xr[10], s); s = fmaf(bfhi(b.y), xr[11], s);
    s = fmaf(bflo(b.z), xr[12], s); s = fmaf(bfhi(b.z), xr[13], s);
    s = fmaf(bflo(b.w), xr[14], s); s = fmaf(bfhi(b.w), xr[15], s);
  } else {
    const float4* p = (const float4*)((const float*)w + base);
    float4 a = p[0], b = p[1], c = p[2], d = p[3];
    s = fmaf(a.x, xr[0],  s); s = fmaf(a.y, xr[1],  s);
    s = fmaf(a.z, xr[2],  s); s = fmaf(a.w, xr[3],  s);
    s = fmaf(b.x, xr[4],  s); s = fmaf(b.y, xr[5],  s);
    s = fmaf(b.z, xr[6],  s); s = fmaf(b.w, xr[7],  s);
    s = fmaf(c.x, xr[8],  s); s = fmaf(c.y, xr[9],  s);
    s = fmaf(c.z, xr[10], s); s = fmaf(c.w, xr[11], s);
    s = fmaf(d.x, xr[12], s); s = fmaf(d.y, xr[13], s);
    s = fmaf(d.z, xr[14], s); s = fmaf(d.w, xr[15], s);
  }
  return s;
}

// ---------------- Threefry-2x32-20 (JAX partitionable scheme) ----------------
__host__ __device__ inline void tf2x32(u32 k0, u32 k1, u32 x0, u32 x1, u32& o0, u32& o1){
  u32 k2 = k0 ^ k1 ^ 0x1BD11BDAu;
  x0 += k0; x1 += k1;
#define TFR(r) { x0 += x1; x1 = (x1 << r) | (x1 >> (32 - r)); x1 ^= x0; }
  TFR(13) TFR(15) TFR(26) TFR(6)  x0 += k1; x1 += k2 + 1u;
  TFR(17) TFR(29) TFR(16) TFR(24) x0 += k2; x1 += k0 + 2u;
  TFR(13) TFR(15) TFR(26) TFR(6)  x0 += k0; x1 += k1 + 3u;
  TFR(17) TFR(29) TFR(16) TFR(24) x0 += k1; x1 += k2 + 4u;
  TFR(13) TFR(15) TFR(26) TFR(6)  x0 += k2; x1 += k0 + 5u;
#undef TFR
  o0 = x0; o1 = x1;
}
DEV bool keep_mask(u32 k0, u32 k1, u32 idx){
  u32 a, b; tf2x32(k0, k1, 0u, idx, a, b);
  return (((a ^ b) >> 31) & 1u) == 0u;
}

// ---------------- dtype detector ----------------
// fp32 N(0,1) words: exponent field ~[99..135]. bf16-pair words: >=~240 (or tiny).
__global__ void detect_kernel(const u32* __restrict__ mem, int* __restrict__ flag){
  if (threadIdx.x == 0 && blockIdx.x == 0){
    int cnt = 0;
    for (int i = 0; i < 64; i++){
      u32 e = (mem[i] >> 23) & 0xFFu;
      if (e >= 90u && e <= 160u) cnt++;
    }
    flag[0] = (cnt >= 48) ? 0 : 1;   // 0 = fp32, 1 = bf16
  }
}

// ---------------- grid barrier ----------------
DEV void gridbar(int* flags, int target){
  __threadfence();
  __syncthreads();
  if ((int)threadIdx.x == (int)blockIdx.x){
    __hip_atomic_store(&flags[blockIdx.x * 16], target, __ATOMIC_RELEASE, __HIP_MEMORY_SCOPE_AGENT);
  }
  int* myf = &flags[threadIdx.x * 16];
  while (__hip_atomic_load(myf, __ATOMIC_ACQUIRE, __HIP_MEMORY_SCOPE_AGENT) < target){
    __builtin_amdgcn_s_sleep(2);
  }
  __syncthreads();
  __threadfence();
}

// ---------------- LSTM GEMV stage ----------------
// x = [xs0 (nc0 chunks of 256, f32 internal), ctx (2 chunks), h (4 chunks)]
DEV void lstm_stage(const float* __restrict__ xs0, int st0, int nc0,
                    const float* __restrict__ ctxp,
                    const float* __restrict__ hsrc,
                    const void* __restrict__ w_ih, int Kih,
                    const void* __restrict__ w_hh,
                    const void* __restrict__ b_ih, const void* __restrict__ b_hh,
                    float* __restrict__ creg,
                    float* __restrict__ hdst, float* lds, bool bf){
  const int tid = threadIdx.x;
  const int bb = tid >> 4, l = tid & 15;
  const int j0 = blockIdx.x * 4;
  const int ncx = nc0 + 2, nct = ncx + 4;
  float acc[16];
#pragma unroll
  for (int i = 0; i < 16; i++) acc[i] = 0.f;

  for (int c = 0; c < nct; c++){
    __syncthreads();
    for (int it = 0; it < 16; it++){
      const float* src;
      if (c < nc0)       src = xs0  + it * st0  + c * 256;
      else if (c < ncx)  src = ctxp + it * EDIM + (c - nc0) * 256;
      else               src = hsrc + it * ARNN + (c - ncx) * 256;
      lds[it * 264 + tid] = src[tid];
    }
    __syncthreads();
    float xr[16];
    const float* xb = &lds[bb * 264 + l * 16];
#pragma unroll
    for (int i = 0; i < 16; i++) xr[i] = xb[i];

    const void* wseg; size_t K, koff;
    if (c < ncx){ wseg = w_ih; K = (size_t)Kih; koff = (size_t)c * 256; }
    else        { wseg = w_hh; K = ARNN; koff = (size_t)(c - ncx) * 256; }
#pragma unroll
    for (int j = 0; j < 4; j++){
#pragma unroll
      for (int g = 0; g < 4; g++){
        size_t base = (size_t)(g * ARNN + j0 + j) * K + koff + (size_t)l * 16;
        acc[j * 4 + g] += dot16a(wseg, base, xr, bf);
      }
    }
  }
#pragma unroll
  for (int i = 0; i < 16; i++){
    float v = acc[i];
    v += __shfl_xor(v, 8, 16);
    v += __shfl_xor(v, 4, 16);
    v += __shfl_xor(v, 2, 16);
    v += __shfl_xor(v, 1, 16);
    acc[i] = v;
  }
  if (l == 0){
#pragma unroll
    for (int j = 0; j < 4; j++){
      int jj = j0 + j;
      float gi = acc[j*4+0] + ldv(b_ih, jj, bf)          + ldv(b_hh, jj, bf);
      float gf = acc[j*4+1] + ldv(b_ih, ARNN+jj, bf)     + ldv(b_hh, ARNN+jj, bf);
      float gg = acc[j*4+2] + ldv(b_ih, 2*ARNN+jj, bf)   + ldv(b_hh, 2*ARNN+jj, bf);
      float go = acc[j*4+3] + ldv(b_ih, 3*ARNN+jj, bf)   + ldv(b_hh, 3*ARNN+jj, bf);
      float cn = fsig(gf) * creg[j] + fsig(gi) * ftanh(gg);
      creg[j] = cn;
      hdst[bb * ARNN + jj] = fsig(go) * ftanh(cn);
    }
  }
}

// mel/gate projection for step pt
DEV void proj_stage(const float* __restrict__ dech, const float* __restrict__ ctxb,
                    const void* __restrict__ proj_w, const void* __restrict__ proj_b,
                    const void* __restrict__ gate_w, const void* __restrict__ gate_b,
                    void* __restrict__ out, int b, int pt, float* lds, bool bf){
  int tid = threadIdx.x;
  for (int i = tid; i < ARNN; i += 256) lds[i] = dech[b * ARNN + i];
  for (int i = tid; i < EDIM; i += 256) lds[ARNN + i] = ctxb[b * EDIM + i];
  __syncthreads();
  if (tid < 81){
    const void* w = (tid < 80) ? proj_w : gate_w;
    size_t rb = (tid < 80) ? (size_t)tid * 1536 : 0;
    float s = (tid < 80) ? ldv(proj_b, tid, bf) : ldv(gate_b, 0, bf);
    for (int k = 0; k < 1536; k += 16) s += dot16a(w, rb + k, &lds[k], bf);
    if (tid < 80) stv(out, (size_t)b * (NMEL * T_DEC) + (size_t)tid * T_DEC + pt, s, bf);
    else          stv(out, (size_t)OUT_GATE + (size_t)b * T_DEC + pt, s, bf);
  }
  __syncthreads();
}

// ---------------- persistent decoder ----------------
__global__ void __launch_bounds__(256) decoder_kernel(
    const void* __restrict__ memory, const void* __restrict__ mels,
    const void* __restrict__ prenet_w1, const void* __restrict__ prenet_w2,
    const void* __restrict__ mem_w,
    const void* __restrict__ query_w, const void* __restrict__ v_w,
    const void* __restrict__ att_w_ih, const void* __restrict__ att_w_hh,
    const void* __restrict__ att_b_ih, const void* __restrict__ att_b_hh,
    const void* __restrict__ dec_w_ih, const void* __restrict__ dec_w_hh,
    const void* __restrict__ dec_b_ih, const void* __restrict__ dec_b_hh,
    const void* __restrict__ proj_w, const void* __restrict__ proj_b,
    const void* __restrict__ gate_w, const void* __restrict__ gate_b,
    float* __restrict__ ws, void* __restrict__ out,
    u32 k10, u32 k11, u32 k20, u32 k21, int wsok_state, int wsok_pm)
{
  __shared__ float lds[4624];   // [0..4223] staging; [4224..4623] persistent align (blk<16)
  int* flags = (int*)ws;
  const bool bf = (((const int*)ws)[4095] != 0);
  u16* pm_t = (u16*)((char*)ws + (size_t)NEED_STATE);  // bf16 [b][a][e]
  int bar = 0;
  const int blk = blockIdx.x;
  const int tid = threadIdx.x;

  if (!wsok_state){   // ws catastrophically small: sentinel and bail
    if (blk == 0 && tid == 0) stv(out, 0, 123.0f, bf);
    return;
  }

  float creg_att[4] = {0.f, 0.f, 0.f, 0.f};
  float creg_dec[4] = {0.f, 0.f, 0.f, 0.f};

  // ---- pre-loop: align init + processed-memory (block b computes batch b) ----
  if (blk < 16){
    const int b = blk;
    if (tid < T_ENC) lds[4224 + tid] = (tid == 0) ? 1.0f : 0.0f;
    for (int e = 0; e < T_ENC; e++){
      float v0, v1;
      if (bf){
        u32 mv = ((const u32*)memory)[((size_t)b * T_ENC + e) * EDIM / 2 + tid];
        v0 = bflo(mv); v1 = bfhi(mv);
      } else {
        const float* mp = (const float*)memory + ((size_t)b * T_ENC + e) * EDIM;
        v0 = mp[2 * tid]; v1 = mp[2 * tid + 1];
      }
      __syncthreads();
      lds[2 * tid] = v0; lds[2 * tid + 1] = v1;
      __syncthreads();
      if (tid < ADIM && wsok_pm){
        float s = 0.f;
        for (int k = 0; k < EDIM; k += 16) s += dot16a(mem_w, (size_t)tid * EDIM + k, &lds[k], bf);
        pm_t[((size_t)b * ADIM + tid) * T_ENC + e] = f2bf(s);
      }
    }
    __syncthreads();
  }

  for (int t = 0; t < T_DEC; t++){
    const int rp = t & 1, wp = rp ^ 1;

    // ---- stage 1: attention LSTM (all blocks) ----
    lstm_stage(ws + OFF_PRENET + rp * (NB * PDIM), PDIM, 1,
               ws + OFF_CTX + rp * (NB * EDIM),
               ws + OFF_ATT_H + rp * (NB * ARNN),
               att_w_ih, 768, att_w_hh, att_b_ih, att_b_hh,
               creg_att, ws + OFF_ATT_H + wp * (NB * ARNN), lds, bf);
    gridbar(flags, ++bar);

    // ---- stage 2 ----
    if (blk < 16){
      const int b = blk;
      float* s_h  = lds;
      float* s_pq = lds + 1024;
      float* s_v  = lds + 1152;
      float* s_p  = lds + 1280;
      float* al_r = lds + 4224 + rp * T_ENC;
      float* al_w = lds + 4224 + wp * T_ENC;
      const float* hb = ws + OFF_ATT_H + wp * (NB * ARNN) + b * ARNN;
      for (int i = tid; i < ARNN; i += 256) s_h[i] = hb[i];
      if (tid < ADIM) s_v[tid] = ldv(v_w, tid, bf);
      __syncthreads();
      if (tid < ADIM){
        float s = 0.f;
        for (int k = 0; k < ARNN; k += 16) s += dot16a(query_w, (size_t)tid * ARNN + k, &s_h[k], bf);
        s_pq[tid] = s;
      }
      __syncthreads();
      if (tid < T_ENC){
        const u16* pmr = pm_t + (size_t)b * ADIM * T_ENC + tid;
        float e = 0.f;
        for (int a = 0; a < ADIM; a++){
          float pmv = wsok_pm ? bf2f(pmr[(size_t)a * T_ENC]) : 0.f;
          e += s_v[a] * ftanh(s_pq[a] + pmv);
        }
        s_p[tid] = fsig(e);
      }
      __syncthreads();
      if (tid < T_ENC){
        float an = al_r[tid] * s_p[tid];
        if (tid > 0) an += al_r[tid - 1] * (1.f - s_p[tid - 1]);
        al_w[tid] = an;
        stv(out, (size_t)OUT_ALIGN + (size_t)b * (T_DEC * T_ENC) + (size_t)t * T_ENC + tid, an, bf);
      }
      __syncthreads();
      {
        float c0 = 0.f, c1 = 0.f;
        const int e0 = tid * 2;
        if (bf){
          const u16* mb = (const u16*)memory + (size_t)b * T_ENC * EDIM + e0;
          for (int s2 = 0; s2 < T_ENC; s2++){
            float as = al_w[s2];
            u32 mv = *(const u32*)(mb + (size_t)s2 * EDIM);
            c0 = fmaf(bflo(mv), as, c0);
            c1 = fmaf(bfhi(mv), as, c1);
          }
        } else {
          const float* mb = (const float*)memory + (size_t)b * T_ENC * EDIM + e0;
          for (int s2 = 0; s2 < T_ENC; s2++){
            float as = al_w[s2];
            c0 = fmaf(mb[(size_t)s2 * EDIM],     as, c0);
            c1 = fmaf(mb[(size_t)s2 * EDIM + 1], as, c1);
          }
        }
        float* cw = ws + OFF_CTX + wp * (NB * EDIM) + b * EDIM;
        cw[e0] = c0; cw[e0 + 1] = c1;
      }
    } else if (blk < 32){
      if (t > 0)
        proj_stage(ws + OFF_DEC_H + rp * (NB * ARNN), ws + OFF_CTX + rp * (NB * EDIM),
                   proj_w, proj_b, gate_w, gate_b, out, blk - 16, t - 1, lds, bf);
    } else if (blk < 40){
      if (t < T_DEC - 1){
        const int tt = t + 1;
        for (int b2 = 0; b2 < 2; b2++){
          const int b = (blk - 32) * 2 + b2;
          if (tid < NMEL) lds[tid] = ldv(mels, ((size_t)b * NMEL + tid) * T_DEC + t, bf);
          __syncthreads();
          {
            float s = 0.f;
            for (int k = 0; k < NMEL; k += 16) s += dot16a(prenet_w1, (size_t)tid * NMEL + k, &lds[k], bf);
            s = fmaxf(s, 0.f);
            u32 idx = (u32)((tt * NB + b) * PDIM + tid);
            lds[128 + tid] = keep_mask(k10, k11, idx) ? 2.f * s : 0.f;
          }
          __syncthreads();
          {
            float s = 0.f;
            for (int k = 0; k < PDIM; k += 16) s += dot16a(prenet_w2, (size_t)tid * PDIM + k, &lds[128 + k], bf);
            s = fmaxf(s, 0.f);
            u32 idx = (u32)((tt * NB + b) * PDIM + tid);
            ws[OFF_PRENET + wp * (NB * PDIM) + b * PDIM + tid] =
                keep_mask(k20, k21, idx) ? 2.f * s : 0.f;
          }
          __syncthreads();
        }
      }
    }
    gridbar(flags, ++bar);

    // ---- stage 3: decoder LSTM (all blocks) ----
    lstm_stage(ws + OFF_ATT_H + wp * (NB * ARNN), ARNN, 4,
               ws + OFF_CTX + wp * (NB * EDIM),
               ws + OFF_DEC_H + rp * (NB * ARNN),
               dec_w_ih, 1536, dec_w_hh, dec_b_ih, dec_b_hh,
               creg_dec, ws + OFF_DEC_H + wp * (NB * ARNN), lds, bf);
    gridbar(flags, ++bar);
  }

  // final projection for t = 299 (state parity 0)
  if (blk >= 16 && blk < 32){
    proj_stage(ws + OFF_DEC_H + 0, ws + OFF_CTX + 0,
               proj_w, proj_b, gate_w, gate_b, out, blk - 16, T_DEC - 1, lds, bf);
  }
}

// ---------------- launch ----------------
extern "C" void kernel_launch(void* const* d_in, const int* in_sizes, int n_in,
                              void* d_out, int out_size, void* d_ws, size_t ws_size,
                              hipStream_t stream){
  float* ws = (float*)d_ws;
  int wsok_state = (ws_size >= (size_t)NEED_STATE) ? 1 : 0;
  int wsok_pm    = (ws_size >= (size_t)NEED_PM)    ? 1 : 0;

  size_t zbytes = (size_t)NEED_STATE;
  if (zbytes > ws_size) zbytes = ws_size;
  hipMemsetAsync(d_ws, 0, zbytes, stream);

  u32 k10, k11, k20, k21;
  tf2x32(0u, 42u, 0u, 0u, k10, k11);
  tf2x32(0u, 42u, 0u, 1u, k20, k21);

  hipLaunchKernelGGL(detect_kernel, dim3(1), dim3(64), 0, stream,
                     (const u32*)d_in[0], (int*)d_ws + 4095);
  hipLaunchKernelGGL(decoder_kernel, dim3(256), dim3(256), 0, stream,
                     d_in[0], d_in[1], d_in[2], d_in[3], d_in[4], d_in[5], d_in[6],
                     d_in[7], d_in[8], d_in[9], d_in[10],
                     d_in[11], d_in[12], d_in[13], d_in[14],
                     d_in[15], d_in[16], d_in[17], d_in[18],
                     ws, d_out, k10, k11, k20, k21, wsok_state, wsok_pm);
}

// Round 7
// 93446.954 us; speedup vs baseline: 1.9210x; 1.9210x over previous
//
#include <hip/hip_runtime.h>

typedef unsigned int u32;
typedef unsigned short u16;
#define DEV __device__ __forceinline__

// ---------------- problem sizes ----------------
#define T_DEC 300
#define NB    16
#define T_ENC 200
#define EDIM  512
#define ARNN  1024
#define PDIM  256
#define ADIM  128
#define NMEL  80

// ---------------- ws layout ----------------
// ints [0..4095]: barrier flags (block i at [i*16]); abort flag at [4081]
#define ABORT_IDX   4081
#define OFF_ATT_H   4096                     // 2 * 16*1024 f32
#define OFF_DEC_H   (OFF_ATT_H + 2*NB*ARNN)
#define OFF_CTX     (OFF_DEC_H + 2*NB*ARNN)  // 2 * 16*512
#define OFF_PRENET  (OFF_CTX + 2*NB*EDIM)    // 2 * 16*256
#define OFF_F32_END (OFF_PRENET + 2*NB*PDIM) // 94208 f32 = 376832 B
#define NEED_STATE  (OFF_F32_END * 4)
#define NEED_PM     (NEED_STATE + NB*ADIM*T_ENC*2)   // + 819200 B (pm bf16)

#define SPIN_LIMIT  20000000

// ---------------- out layout (f32 elements) ----------------
#define OUT_GATE  (NB*NMEL*T_DEC)        // 384000
#define OUT_ALIGN (OUT_GATE + NB*T_DEC)  // 388800

// ---------------- helpers ----------------
DEV float bf2f(u16 h){ return __uint_as_float(((u32)h) << 16); }
DEV u16 f2bf(float f){
  u32 u = __float_as_uint(f);
  return (u16)((u + 0x7fffu + ((u >> 16) & 1u)) >> 16);
}
DEV float fsig(float x){ return 1.0f / (1.0f + __expf(-x)); }
DEV float ftanh(float x){
  float xx = fminf(15.0f, fmaxf(-15.0f, x));
  float e = __expf(2.0f * xx);
  return (e - 1.0f) / (e + 1.0f);
}

// 16-element fp32 weight x f32 dot (wr must be 16-float aligned)
DEV float dot16f(const float* __restrict__ wr, const float* __restrict__ xr){
  const float4* p = (const float4*)wr;
  float4 a = p[0], b = p[1], c = p[2], d = p[3];
  float s = 0.f;
  s = fmaf(a.x, xr[0],  s); s = fmaf(a.y, xr[1],  s);
  s = fmaf(a.z, xr[2],  s); s = fmaf(a.w, xr[3],  s);
  s = fmaf(b.x, xr[4],  s); s = fmaf(b.y, xr[5],  s);
  s = fmaf(b.z, xr[6],  s); s = fmaf(b.w, xr[7],  s);
  s = fmaf(c.x, xr[8],  s); s = fmaf(c.y, xr[9],  s);
  s = fmaf(c.z, xr[10], s); s = fmaf(c.w, xr[11], s);
  s = fmaf(d.x, xr[12], s); s = fmaf(d.y, xr[13], s);
  s = fmaf(d.z, xr[14], s); s = fmaf(d.w, xr[15], s);
  return s;
}

// ---------------- Threefry-2x32-20 (JAX partitionable; R3-verified) ----------------
__host__ __device__ inline void tf2x32(u32 k0, u32 k1, u32 x0, u32 x1, u32& o0, u32& o1){
  u32 k2 = k0 ^ k1 ^ 0x1BD11BDAu;
  x0 += k0; x1 += k1;
#define TFR(r) { x0 += x1; x1 = (x1 << r) | (x1 >> (32 - r)); x1 ^= x0; }
  TFR(13) TFR(15) TFR(26) TFR(6)  x0 += k1; x1 += k2 + 1u;
  TFR(17) TFR(29) TFR(16) TFR(24) x0 += k2; x1 += k0 + 2u;
  TFR(13) TFR(15) TFR(26) TFR(6)  x0 += k0; x1 += k1 + 3u;
  TFR(17) TFR(29) TFR(16) TFR(24) x0 += k1; x1 += k2 + 4u;
  TFR(13) TFR(15) TFR(26) TFR(6)  x0 += k2; x1 += k0 + 5u;
#undef TFR
  o0 = x0; o1 = x1;
}
DEV bool keep_mask(u32 k0, u32 k1, u32 idx){
  u32 a, b; tf2x32(k0, k1, 0u, idx, a, b);
  return (((a ^ b) >> 31) & 1u) == 0u;
}

__global__ void sentinel_kernel(float* out){ if (threadIdx.x == 0) out[0] = 123.0f; }

// ---------------- grid barrier: relaxed poll + single acquire (R6-verified) ----------------
DEV bool gridbar(int* flags, int target, int blk, int tid, float* out){
  __threadfence();
  __syncthreads();
  if (tid == 0)
    __hip_atomic_store(&flags[blk * 16], target, __ATOMIC_RELEASE, __HIP_MEMORY_SCOPE_AGENT);
  int* myf = &flags[tid * 16];
  int tries = 0, aborted = 0;
  while (__hip_atomic_load(myf, __ATOMIC_RELAXED, __HIP_MEMORY_SCOPE_AGENT) < target){
    if (++tries > SPIN_LIMIT){
      __hip_atomic_store(&flags[ABORT_IDX], 1, __ATOMIC_RELAXED, __HIP_MEMORY_SCOPE_AGENT);
      out[1] = 55.0f;
      aborted = 1; break;
    }
    if ((tries & 2047) == 0 &&
        __hip_atomic_load(&flags[ABORT_IDX], __ATOMIC_RELAXED, __HIP_MEMORY_SCOPE_AGENT) != 0){
      aborted = 1; break;
    }
    __builtin_amdgcn_s_sleep(2);
  }
  if (__syncthreads_or(aborted)) return false;
  if (tid == 0)
    (void)__hip_atomic_load(&flags[blk * 16], __ATOMIC_ACQUIRE, __HIP_MEMORY_SCOPE_AGENT);
  __syncthreads();
  return true;
}

// ---------------- LSTM GEMV stage (R3-verified numerics, fp32 weights) ----------------
DEV void lstm_stage(const float* __restrict__ xs0, int st0, int nc0,
                    const float* __restrict__ ctxp,
                    const float* __restrict__ hsrc,
                    const float* __restrict__ w_ih, int Kih,
                    const float* __restrict__ w_hh,
                    const float* __restrict__ b_ih, const float* __restrict__ b_hh,
                    float* __restrict__ creg,
                    float* __restrict__ hdst, float* lds){
  const int tid = threadIdx.x;
  const int bb = tid >> 4, l = tid & 15;
  const int j0 = blockIdx.x * 4;
  const int ncx = nc0 + 2, nct = ncx + 4;
  float acc[16];
#pragma unroll
  for (int i = 0; i < 16; i++) acc[i] = 0.f;

  for (int c = 0; c < nct; c++){
    __syncthreads();
    for (int it = 0; it < 16; it++){
      const float* src;
      if (c < nc0)       src = xs0  + it * st0  + c * 256;
      else if (c < ncx)  src = ctxp + it * EDIM + (c - nc0) * 256;
      else               src = hsrc + it * ARNN + (c - ncx) * 256;
      lds[it * 264 + tid] = src[tid];
    }
    __syncthreads();
    float xr[16];
    const float* xb = &lds[bb * 264 + l * 16];
#pragma unroll
    for (int i = 0; i < 16; i++) xr[i] = xb[i];

    const float* wseg; size_t K, koff;
    if (c < ncx){ wseg = w_ih; K = (size_t)Kih; koff = (size_t)c * 256; }
    else        { wseg = w_hh; K = ARNN; koff = (size_t)(c - ncx) * 256; }
#pragma unroll
    for (int j = 0; j < 4; j++){
#pragma unroll
      for (int g = 0; g < 4; g++){
        const float* wr = wseg + (size_t)(g * ARNN + j0 + j) * K + koff + (size_t)l * 16;
        acc[j * 4 + g] += dot16f(wr, xr);
      }
    }
  }
#pragma unroll
  for (int i = 0; i < 16; i++){
    float v = acc[i];
    v += __shfl_xor(v, 8, 16);
    v += __shfl_xor(v, 4, 16);
    v += __shfl_xor(v, 2, 16);
    v += __shfl_xor(v, 1, 16);
    acc[i] = v;
  }
  if (l == 0){
#pragma unroll
    for (int j = 0; j < 4; j++){
      int jj = j0 + j;
      float gi = acc[j*4+0] + b_ih[jj]        + b_hh[jj];
      float gf = acc[j*4+1] + b_ih[ARNN+jj]   + b_hh[ARNN+jj];
      float gg = acc[j*4+2] + b_ih[2*ARNN+jj] + b_hh[2*ARNN+jj];
      float go = acc[j*4+3] + b_ih[3*ARNN+jj] + b_hh[3*ARNN+jj];
      float cn = fsig(gf) * creg[j] + fsig(gi) * ftanh(gg);
      creg[j] = cn;
      hdst[bb * ARNN + jj] = fsig(go) * ftanh(cn);
    }
  }
}

// mel/gate projection for step pt (fp32)
DEV void proj_stage(const float* __restrict__ dech, const float* __restrict__ ctxb,
                    const float* __restrict__ proj_w, const float* __restrict__ proj_b,
                    const float* __restrict__ gate_w, const float* __restrict__ gate_b,
                    float* __restrict__ out, int b, int pt, float* lds){
  int tid = threadIdx.x;
  for (int i = tid; i < ARNN; i += 256) lds[i] = dech[b * ARNN + i];
  for (int i = tid; i < EDIM; i += 256) lds[ARNN + i] = ctxb[b * EDIM + i];
  __syncthreads();
  if (tid < 81){
    const float* wr = (tid < 80) ? proj_w + (size_t)tid * 1536 : gate_w;
    float s = (tid < 80) ? proj_b[tid] : gate_b[0];
    for (int k = 0; k < 1536; k += 16) s += dot16f(wr + k, &lds[k]);
    if (tid < 80) out[(size_t)b * (NMEL * T_DEC) + (size_t)tid * T_DEC + pt] = s;
    else          out[OUT_GATE + (size_t)b * T_DEC + pt] = s;
  }
  __syncthreads();
}

// ---------------- persistent decoder ----------------
__global__ void __launch_bounds__(256) decoder_kernel(
    const float* __restrict__ memory, const float* __restrict__ mels,
    const float* __restrict__ prenet_w1, const float* __restrict__ prenet_w2,
    const float* __restrict__ mem_w,
    const float* __restrict__ query_w, const float* __restrict__ v_w,
    const float* __restrict__ att_w_ih, const float* __restrict__ att_w_hh,
    const float* __restrict__ att_b_ih, const float* __restrict__ att_b_hh,
    const float* __restrict__ dec_w_ih, const float* __restrict__ dec_w_hh,
    const float* __restrict__ dec_b_ih, const float* __restrict__ dec_b_hh,
    const float* __restrict__ proj_w, const float* __restrict__ proj_b,
    const float* __restrict__ gate_w, const float* __restrict__ gate_b,
    float* __restrict__ ws, float* __restrict__ out,
    u32 k10, u32 k11, u32 k20, u32 k21)
{
  __shared__ float lds[4624];   // [0..4223] staging/temps; [4224..4623] persistent align (blk<16)
  int* flags = (int*)ws;
  u16* pm_t = (u16*)((char*)ws + (size_t)NEED_STATE);  // bf16 [b][a][e] (R3-verified precision)
  int bar = 0;
  const int blk = blockIdx.x;
  const int tid = threadIdx.x;

  float creg_att[4] = {0.f, 0.f, 0.f, 0.f};
  float creg_dec[4] = {0.f, 0.f, 0.f, 0.f};

  // ---- pre-loop: align init + processed-memory (block b computes batch b) ----
  if (blk < 16){
    const int b = blk;
    if (tid < T_ENC) lds[4224 + tid] = (tid == 0) ? 1.0f : 0.0f;
    const float2* m2 = (const float2*)memory;
    for (int e = 0; e < T_ENC; e++){
      float2 mv = m2[((size_t)b * T_ENC + e) * (EDIM / 2) + tid];
      __syncthreads();
      lds[2 * tid] = mv.x; lds[2 * tid + 1] = mv.y;
      __syncthreads();
      if (tid < ADIM){
        const float* wr = mem_w + (size_t)tid * EDIM;
        float s = 0.f;
        for (int k = 0; k < EDIM; k += 16) s += dot16f(wr + k, &lds[k]);
        pm_t[((size_t)b * ADIM + tid) * T_ENC + e] = f2bf(s);
      }
    }
    __syncthreads();
  }

  for (int t = 0; t < T_DEC; t++){
    const int rp = t & 1, wp = rp ^ 1;

    // ---- stage 1: attention LSTM (all blocks) ----
    lstm_stage(ws + OFF_PRENET + rp * (NB * PDIM), PDIM, 1,
               ws + OFF_CTX + rp * (NB * EDIM),
               ws + OFF_ATT_H + rp * (NB * ARNN),
               att_w_ih, 768, att_w_hh, att_b_ih, att_b_hh,
               creg_att, ws + OFF_ATT_H + wp * (NB * ARNN), lds);
    if (!gridbar(flags, ++bar, blk, tid, out)) return;

    // ---- stage 2 ----
    if (blk < 16){
      const int b = blk;
      float* s_h  = lds;
      float* s_pq = lds + 1024;
      float* s_v  = lds + 1152;
      float* s_p  = lds + 1280;
      float* al_r = lds + 4224 + rp * T_ENC;
      float* al_w = lds + 4224 + wp * T_ENC;
      const float* hb = ws + OFF_ATT_H + wp * (NB * ARNN) + b * ARNN;
      for (int i = tid; i < ARNN; i += 256) s_h[i] = hb[i];
      if (tid < ADIM) s_v[tid] = v_w[tid];
      __syncthreads();
      if (tid < ADIM){
        const float* qr = query_w + (size_t)tid * ARNN;
        float s = 0.f;
        for (int k = 0; k < ARNN; k += 16) s += dot16f(qr + k, &s_h[k]);
        s_pq[tid] = s;
      }
      __syncthreads();
      if (tid < T_ENC){
        const u16* pmr = pm_t + (size_t)b * ADIM * T_ENC + tid;
        float e = 0.f;
        for (int a = 0; a < ADIM; a++)
          e += s_v[a] * ftanh(s_pq[a] + bf2f(pmr[(size_t)a * T_ENC]));
        s_p[tid] = fsig(e);
      }
      __syncthreads();
      if (tid < T_ENC){
        float an = al_r[tid] * s_p[tid];
        if (tid > 0) an += al_r[tid - 1] * (1.f - s_p[tid - 1]);
        al_w[tid] = an;
        out[OUT_ALIGN + (size_t)(b * T_DEC + t) * T_ENC + tid] = an;
      }
      __syncthreads();
      {
        const int e0 = tid * 2;
        const float2* mb = (const float2*)(memory + (size_t)b * T_ENC * EDIM) + tid;
        float c0 = 0.f, c1 = 0.f;
        for (int s2 = 0; s2 < T_ENC; s2++){
          float as = al_w[s2];
          float2 mv = mb[(size_t)s2 * (EDIM / 2)];
          c0 = fmaf(mv.x, as, c0);
          c1 = fmaf(mv.y, as, c1);
        }
        float* cw = ws + OFF_CTX + wp * (NB * EDIM) + b * EDIM;
        cw[e0] = c0; cw[e0 + 1] = c1;
      }
    } else if (blk < 32){
      if (t > 0)
        proj_stage(ws + OFF_DEC_H + rp * (NB * ARNN), ws + OFF_CTX + rp * (NB * EDIM),
                   proj_w, proj_b, gate_w, gate_b, out, blk - 16, t - 1, lds);
    } else if (blk < 40){
      if (t < T_DEC - 1){
        const int tt = t + 1;
        for (int b2 = 0; b2 < 2; b2++){
          const int b = (blk - 32) * 2 + b2;
          if (tid < NMEL) lds[tid] = mels[(size_t)(b * NMEL + tid) * T_DEC + t];
          __syncthreads();
          {
            const float* wr = prenet_w1 + (size_t)tid * NMEL;
            float s = 0.f;
            for (int k = 0; k < NMEL; k += 16) s += dot16f(wr + k, &lds[k]);
            s = fmaxf(s, 0.f);
            u32 idx = (u32)((tt * NB + b) * PDIM + tid);
            lds[128 + tid] = keep_mask(k10, k11, idx) ? 2.f * s : 0.f;
          }
          __syncthreads();
          {
            const float* wr = prenet_w2 + (size_t)tid * PDIM;
            float s = 0.f;
            for (int k = 0; k < PDIM; k += 16) s += dot16f(wr + k, &lds[128 + k]);
            s = fmaxf(s, 0.f);
            u32 idx = (u32)((tt * NB + b) * PDIM + tid);
            ws[OFF_PRENET + wp * (NB * PDIM) + b * PDIM + tid] =
                keep_mask(k20, k21, idx) ? 2.f * s : 0.f;
          }
          __syncthreads();
        }
      }
    }
    if (!gridbar(flags, ++bar, blk, tid, out)) return;

    // ---- stage 3: decoder LSTM (all blocks) ----
    lstm_stage(ws + OFF_ATT_H + wp * (NB * ARNN), ARNN, 4,
               ws + OFF_CTX + wp * (NB * EDIM),
               ws + OFF_DEC_H + rp * (NB * ARNN),
               dec_w_ih, 1536, dec_w_hh, dec_b_ih, dec_b_hh,
               creg_dec, ws + OFF_DEC_H + wp * (NB * ARNN), lds);
    if (!gridbar(flags, ++bar, blk, tid, out)) return;
  }

  // ---- final projection for t = 299 (state parity 0) ----
  if (blk >= 16 && blk < 32){
    proj_stage(ws + OFF_DEC_H + 0, ws + OFF_CTX + 0,
               proj_w, proj_b, gate_w, gate_b, out, blk - 16, T_DEC - 1, lds);
  }
}

// ---------------- launch ----------------
extern "C" void kernel_launch(void* const* d_in, const int* in_sizes, int n_in,
                              void* d_out, int out_size, void* d_ws, size_t ws_size,
                              hipStream_t stream){
  if (ws_size < (size_t)NEED_PM){
    hipLaunchKernelGGL(sentinel_kernel, dim3(1), dim3(64), 0, stream, (float*)d_out);
    return;
  }
  float* ws = (float*)d_ws;
  hipMemsetAsync(d_ws, 0, (size_t)NEED_STATE, stream);

  u32 k10, k11, k20, k21;
  tf2x32(0u, 42u, 0u, 0u, k10, k11);
  tf2x32(0u, 42u, 0u, 1u, k20, k21);

  hipLaunchKernelGGL(decoder_kernel, dim3(256), dim3(256), 0, stream,
                     (const float*)d_in[0], (const float*)d_in[1],
                     (const float*)d_in[2], (const float*)d_in[3],
                     (const float*)d_in[4], (const float*)d_in[5], (const float*)d_in[6],
                     (const float*)d_in[7], (const float*)d_in[8],
                     (const float*)d_in[9], (const float*)d_in[10],
                     (const float*)d_in[11], (const float*)d_in[12],
                     (const float*)d_in[13], (const float*)d_in[14],
                     (const float*)d_in[15], (const float*)d_in[16],
                     (const float*)d_in[17], (const float*)d_in[18],
                     ws, (float*)d_out, k10, k11, k20, k21);
}

// Round 8
// 79250.018 us; speedup vs baseline: 2.2651x; 1.1791x over previous
//
#include <hip/hip_runtime.h>

typedef unsigned int u32;
typedef unsigned short u16;
#define DEV __device__ __forceinline__

// ---------------- sizes ----------------
#define T_DEC 300
#define NB    16
#define T_ENC 200
#define EDIM  512
#define ARNN  1024
#define PDIM  256
#define ADIM  128
#define NMEL  80
#define KATT  1792            // 256 prenet + 512 ctx + 1024 h_att
#define KDEC  2560            // 1024 h_att + 512 ctx + 1024 h_dec
#define NBLK  1024
#define NTHR  128
#define SPIN_LIMIT 2000000

// ---------------- ws byte offsets (R4 layout: proven to fit ws_size) ----------------
// int flags[1024] at 0; abort flag at byte WS_GO+8
#define WS_GO     4096
#define WS_ALIGN  4608                      // f32 [2][16][200] = 25600
#define WS_XA     30208                     // f32 [2][1792][16] = 229376
#define WS_XD     259584                    // f32 [2][2560][16] = 327680
#define WS_PM     587264                    // u16 [3200][128] = 819200
#define WS_END    1406464
#define WS_ZERO   587264

// ---------------- out layout (f32 elements) ----------------
#define OUT_GATE  (NB*NMEL*T_DEC)           // 384000
#define OUT_ALIGN (OUT_GATE + NB*T_DEC)     // 388800

// ---------------- helpers ----------------
DEV float bflo(u32 u){ return __uint_as_float(u << 16); }
DEV float bfhi(u32 u){ return __uint_as_float(u & 0xffff0000u); }
DEV float bf2f(u16 h){ return __uint_as_float(((u32)h) << 16); }
DEV u16 f2bf(float f){
  u32 u = __float_as_uint(f);
  return (u16)((u + 0x7fffu + ((u >> 16) & 1u)) >> 16);
}
DEV float fsig(float x){ return 1.0f / (1.0f + __expf(-x)); }
DEV float ftanh(float x){
  float xx = fminf(15.0f, fmaxf(-15.0f, x));
  float e = __expf(2.0f * xx);
  return (e - 1.0f) / (e + 1.0f);
}

// ---------------- Threefry-2x32-20 (JAX partitionable; R3/R7-verified) ----------------
__host__ __device__ inline void tf2x32(u32 k0, u32 k1, u32 x0, u32 x1, u32& o0, u32& o1){
  u32 k2 = k0 ^ k1 ^ 0x1BD11BDAu;
  x0 += k0; x1 += k1;
#define TFR(r) { x0 += x1; x1 = (x1 << r) | (x1 >> (32 - r)); x1 ^= x0; }
  TFR(13) TFR(15) TFR(26) TFR(6)  x0 += k1; x1 += k2 + 1u;
  TFR(17) TFR(29) TFR(16) TFR(24) x0 += k2; x1 += k0 + 2u;
  TFR(13) TFR(15) TFR(26) TFR(6)  x0 += k0; x1 += k1 + 3u;
  TFR(17) TFR(29) TFR(16) TFR(24) x0 += k1; x1 += k2 + 4u;
  TFR(13) TFR(15) TFR(26) TFR(6)  x0 += k2; x1 += k0 + 5u;
#undef TFR
  o0 = x0; o1 = x1;
}
DEV bool keep_mask(u32 k0, u32 k1, u32 idx){
  u32 a, b; tf2x32(k0, k1, 0u, idx, a, b);
  return (((a ^ b) >> 31) & 1u) == 0u;
}

// ---------------- params ----------------
struct KParams {
  const float *memory, *mels, *pw1, *pw2, *mem_w, *qw, *vw;
  const float *aih, *ahh, *abi, *abh, *dih, *dhh, *dbi, *dbh;
  const float *prw, *prb, *gw, *gb;
  char* ws; float* out;
  u32 k10, k11, k20, k21;
};

__global__ void sentinel_kernel(float* out){ if (threadIdx.x == 0) out[0] = 123.0f; }

// ---------------- grid barrier (R6/R7-verified pattern, 1024 flags / 128 thr) ----------------
DEV bool gridbar(int* flags, int* abortf, int target, int blk, int tid, float* out){
  __threadfence();
  __syncthreads();
  if (tid == 0)
    __hip_atomic_store(&flags[blk], target, __ATOMIC_RELEASE, __HIP_MEMORY_SCOPE_AGENT);
  int tries = 0, aborted = 0;
  for (;;){
    int m = 0x7fffffff;
#pragma unroll
    for (int i = 0; i < 8; i++){
      int v = __hip_atomic_load(&flags[tid + i * NTHR], __ATOMIC_RELAXED, __HIP_MEMORY_SCOPE_AGENT);
      m = min(m, v);
    }
    if (m >= target) break;
    if (++tries > SPIN_LIMIT){
      __hip_atomic_store(abortf, 1, __ATOMIC_RELAXED, __HIP_MEMORY_SCOPE_AGENT);
      out[1] = 55.0f;
      aborted = 1; break;
    }
    if ((tries & 1023) == 0 &&
        __hip_atomic_load(abortf, __ATOMIC_RELAXED, __HIP_MEMORY_SCOPE_AGENT) != 0){
      aborted = 1; break;
    }
    __builtin_amdgcn_s_sleep(2);
  }
  if (__syncthreads_or(aborted)) return false;
  if (tid == 0)
    (void)__hip_atomic_load(&flags[blk], __ATOMIC_ACQUIRE, __HIP_MEMORY_SCOPE_AGENT);
  __syncthreads();
  return true;
}

// ---------------- persistent decoder ----------------
__global__ void __launch_bounds__(NTHR, 2) decoder_kernel(KParams P){
  // LDS: WA 14336 + WD 20480 + SCR 4096 + 160 = 39072 B -> 4 blocks/CU (156.7 KB of 160)
  __shared__ __align__(16) u16 WA[KATT * 4];   // [k][gate] bf16 att weights (ih k<768, hh k>=768)
  __shared__ __align__(16) u16 WD[KDEC * 4];   // [k][gate] bf16 dec weights (ih k<1536, hh k>=1536)
  __shared__ __align__(16) float SCR[1024];
  __shared__ float CATT[16], CDEC[16];
  __shared__ float GBA[4], GBD[4];

  const int blk = blockIdx.x, tid = threadIdx.x;
  int* flags  = (int*)P.ws;
  int* abortf = (int*)(P.ws + WS_GO + 8);
  float* ALN = (float*)(P.ws + WS_ALIGN);          // [2][16][200]
  float* XA  = (float*)(P.ws + WS_XA);             // [2][1792][16]
  float* XD  = (float*)(P.ws + WS_XD);             // [2][2560][16]
  u16*   PM  = (u16*)(P.ws + WS_PM);               // [3200][128] bf16
  float* out = P.out;
  int bar = 0;

  // ---- one-time: stage this block's LSTM-unit weights into LDS as bf16 ----
#pragma unroll
  for (int g = 0; g < 4; g++){
    const float* rih = P.aih + (size_t)(g * ARNN + blk) * 768;
    for (int k = tid; k < 768; k += NTHR)  WA[k * 4 + g] = f2bf(rih[k]);
    const float* rhh = P.ahh + (size_t)(g * ARNN + blk) * ARNN;
    for (int k = tid; k < ARNN; k += NTHR) WA[(768 + k) * 4 + g] = f2bf(rhh[k]);
    const float* dih = P.dih + (size_t)(g * ARNN + blk) * 1536;
    for (int k = tid; k < 1536; k += NTHR) WD[k * 4 + g] = f2bf(dih[k]);
    const float* dhh = P.dhh + (size_t)(g * ARNN + blk) * ARNN;
    for (int k = tid; k < ARNN; k += NTHR) WD[(1536 + k) * 4 + g] = f2bf(dhh[k]);
  }
  if (tid < 4){
    GBA[tid] = P.abi[tid * ARNN + blk] + P.abh[tid * ARNN + blk];
    GBD[tid] = P.dbi[tid * ARNN + blk] + P.dbh[tid * ARNN + blk];
  }
  if (tid < 16){ CATT[tid] = 0.f; CDEC[tid] = 0.f; }
  if (blk < 16 && tid == 0) ALN[blk * T_ENC] = 1.0f;   // SMA init, parity 0

  // ---- one-time: processed_memory pm[b*200+te][a] (bf16) ----
  for (int rr = 0; rr < 4; rr++){
    int p = blk + rr * NBLK;
    if (p < NB * T_ENC){
      __syncthreads();
      const float4* mrow = (const float4*)(P.memory + (size_t)p * EDIM);
      float4 v = mrow[tid];
      SCR[4 * tid] = v.x; SCR[4 * tid + 1] = v.y;
      SCR[4 * tid + 2] = v.z; SCR[4 * tid + 3] = v.w;
      __syncthreads();
      const float4* w4 = (const float4*)(P.mem_w + (size_t)tid * EDIM);
      float s = 0.f;
      for (int j = 0; j < 128; j++){
        float4 w = w4[j];
        s = fmaf(w.x, SCR[4 * j], s);     s = fmaf(w.y, SCR[4 * j + 1], s);
        s = fmaf(w.z, SCR[4 * j + 2], s); s = fmaf(w.w, SCR[4 * j + 3], s);
      }
      PM[(size_t)p * 128 + tid] = f2bf(s);
    }
  }

  const int b16 = tid & 15, ks = tid >> 4;

  for (int t = 0; t < T_DEC; t++){
    const int rp = t & 1, wp = rp ^ 1;
    float* XAr = XA + rp * KATT * 16;
    float* XAw = XA + wp * KATT * 16;
    float* XDr = XD + rp * KDEC * 16;
    float* XDw = XD + wp * KDEC * 16;

    // ======== stage 1: attention LSTM, unit j = blk (no barrier before: stage3(t-1) disjoint) ========
    {
      float a0 = 0.f, a1 = 0.f, a2 = 0.f, a3 = 0.f;
      int k = ks;
#pragma unroll 4
      for (int i = 0; i < 224; i++, k += 8){
        float x = XAr[k * 16 + b16];
        uint2 wv = *(const uint2*)&WA[k * 4];
        a0 = fmaf(bflo(wv.x), x, a0);
        a1 = fmaf(bfhi(wv.x), x, a1);
        a2 = fmaf(bflo(wv.y), x, a2);
        a3 = fmaf(bfhi(wv.y), x, a3);
      }
      __syncthreads();
      SCR[tid * 4 + 0] = a0; SCR[tid * 4 + 1] = a1;
      SCR[tid * 4 + 2] = a2; SCR[tid * 4 + 3] = a3;
      __syncthreads();
      if (tid < 64){
        int g = tid >> 4, bb = tid & 15;
        float s = 0.f;
#pragma unroll
        for (int q = 0; q < 8; q++) s += SCR[q * 64 + bb * 4 + g];
        SCR[512 + g * 16 + bb] = s;
      }
      __syncthreads();
      if (tid < 16){
        float gi = SCR[512 + tid] + GBA[0];
        float gf = SCR[528 + tid] + GBA[1];
        float gg = SCR[544 + tid] + GBA[2];
        float go = SCR[560 + tid] + GBA[3];
        float cn = fsig(gf) * CATT[tid] + fsig(gi) * ftanh(gg);
        CATT[tid] = cn;
        float h = fsig(go) * ftanh(cn);
        XAw[(768 + blk) * 16 + tid] = h;
        XDw[blk * 16 + tid] = h;
      }
    }
    if (!gridbar(flags, abortf, ++bar, blk, tid, out)) return;

    // ======== stage 2 (service blocks) ========
    if (blk < 16){
      // ---- attention chain, batch b ----
      const int b = blk;
      for (int i = tid; i < ARNN; i += NTHR) SCR[i] = XAw[(768 + i) * 16 + b];
      __syncthreads();
      float pq = 0.f;
      {
        const float4* q4 = (const float4*)(P.qw + (size_t)tid * ARNN);
        for (int j = 0; j < 256; j++){
          float4 q = q4[j];
          pq = fmaf(q.x, SCR[4 * j], pq);     pq = fmaf(q.y, SCR[4 * j + 1], pq);
          pq = fmaf(q.z, SCR[4 * j + 2], pq); pq = fmaf(q.w, SCR[4 * j + 3], pq);
        }
      }
      __syncthreads();
      SCR[tid] = pq;
      SCR[128 + tid] = P.vw[tid];
      __syncthreads();
#pragma unroll
      for (int pass = 0; pass < 2; pass++){
        int t2 = pass * NTHR + tid;
        if (t2 < T_ENC){
          const u32* pmr = (const u32*)(PM + (size_t)(b * T_ENC + t2) * 128);
          float e = 0.f;
          for (int a2 = 0; a2 < 64; a2++){
            u32 pv = pmr[a2];
            e = fmaf(SCR[128 + 2 * a2],     ftanh(SCR[2 * a2]     + bflo(pv)), e);
            e = fmaf(SCR[128 + 2 * a2 + 1], ftanh(SCR[2 * a2 + 1] + bfhi(pv)), e);
          }
          SCR[256 + t2] = fsig(e);
        }
      }
      __syncthreads();
      const float* alr = ALN + rp * (NB * T_ENC) + b * T_ENC;
      float*       alw = ALN + wp * (NB * T_ENC) + b * T_ENC;
#pragma unroll
      for (int pass = 0; pass < 2; pass++){
        int t2 = pass * NTHR + tid;
        if (t2 < T_ENC){
          float an = alr[t2] * SCR[256 + t2];
          if (t2 > 0) an += alr[t2 - 1] * (1.f - SCR[256 + t2 - 1]);
          SCR[512 + t2] = an;
          alw[t2] = an;
          out[OUT_ALIGN + (size_t)(b * T_DEC + t) * T_ENC + t2] = an;
        }
      }
      __syncthreads();
      {
        const float2* mb = (const float2*)(P.memory + (size_t)b * T_ENC * EDIM);
        float c0 = 0.f, c1 = 0.f, c2 = 0.f, c3 = 0.f;
        for (int s2 = 0; s2 < T_ENC; s2++){
          float as = SCR[512 + s2];
          float2 m1 = mb[(size_t)s2 * 256 + tid];
          float2 m2 = mb[(size_t)s2 * 256 + tid + 128];
          c0 = fmaf(m1.x, as, c0); c1 = fmaf(m1.y, as, c1);
          c2 = fmaf(m2.x, as, c2); c3 = fmaf(m2.y, as, c3);
        }
        int e0 = 2 * tid, e1 = 2 * tid + 256;
        XAw[(256 + e0) * 16 + b] = c0;  XAw[(256 + e0 + 1) * 16 + b] = c1;
        XAw[(256 + e1) * 16 + b] = c2;  XAw[(256 + e1 + 1) * 16 + b] = c3;
        XDw[(1024 + e0) * 16 + b] = c0; XDw[(1024 + e0 + 1) * 16 + b] = c1;
        XDw[(1024 + e1) * 16 + b] = c2; XDw[(1024 + e1 + 1) * 16 + b] = c3;
      }
    } else if (blk < 32){
      // ---- prenet for step t+1, batch b ----
      if (t < T_DEC - 1){
        const int b = blk - 16;
        const int tt = t + 1;
        if (tid < NMEL) SCR[tid] = P.mels[(size_t)(b * NMEL + tid) * T_DEC + t];
        __syncthreads();
#pragma unroll
        for (int pass = 0; pass < 2; pass++){
          int p2 = pass * NTHR + tid;
          const float* wr = P.pw1 + (size_t)p2 * NMEL;
          float s = 0.f;
          for (int m2 = 0; m2 < NMEL; m2++) s = fmaf(wr[m2], SCR[m2], s);
          s = fmaxf(s, 0.f);
          u32 idx = (u32)((tt * NB + b) * PDIM + p2);
          SCR[384 + p2] = keep_mask(P.k10, P.k11, idx) ? 2.f * s : 0.f;
        }
        __syncthreads();
#pragma unroll
        for (int pass = 0; pass < 2; pass++){
          int q2 = pass * NTHR + tid;
          const float* wr = P.pw2 + (size_t)q2 * PDIM;
          float s = 0.f;
          for (int p3 = 0; p3 < PDIM; p3++) s = fmaf(wr[p3], SCR[384 + p3], s);
          s = fmaxf(s, 0.f);
          u32 idx = (u32)((tt * NB + b) * PDIM + q2);
          XAw[q2 * 16 + b] = keep_mask(P.k20, P.k21, idx) ? 2.f * s : 0.f;
        }
      }
    } else if (blk < 48){
      // ---- projection for step t-1, batch b (reads XDr = state written step t-1) ----
      if (t > 0){
        const int b = blk - 32;
        for (int i = tid; i < ARNN; i += NTHR) SCR[i] = XDr[(1536 + i) * 16 + b];
        __syncthreads();
        if (tid < 81){
          const float* wr = (tid < 80) ? P.prw + (size_t)tid * 1536 : P.gw;
          float s = (tid < 80) ? P.prb[tid] : P.gb[0];
          for (int k = 0; k < 1024; k++) s = fmaf(wr[k], SCR[k], s);
          for (int e = 0; e < 512; e++)  s = fmaf(wr[1024 + e], XDr[(1024 + e) * 16 + b], s);
          if (tid < 80) out[(size_t)(b * NMEL + tid) * T_DEC + (t - 1)] = s;
          else          out[OUT_GATE + (size_t)b * T_DEC + (t - 1)] = s;
        }
      }
    }
    if (!gridbar(flags, abortf, ++bar, blk, tid, out)) return;

    // ======== stage 3: decoder LSTM, unit j = blk ========
    {
      float a0 = 0.f, a1 = 0.f, a2 = 0.f, a3 = 0.f;
      int k = ks;
#pragma unroll 4
      for (int i = 0; i < 192; i++, k += 8){          // k < 1536: h_att|ctx (this step)
        float x = XDw[k * 16 + b16];
        uint2 wv = *(const uint2*)&WD[k * 4];
        a0 = fmaf(bflo(wv.x), x, a0);
        a1 = fmaf(bfhi(wv.x), x, a1);
        a2 = fmaf(bflo(wv.y), x, a2);
        a3 = fmaf(bfhi(wv.y), x, a3);
      }
#pragma unroll 4
      for (int i = 192; i < 320; i++, k += 8){        // k >= 1536: h_dec (prev step)
        float x = XDr[k * 16 + b16];
        uint2 wv = *(const uint2*)&WD[k * 4];
        a0 = fmaf(bflo(wv.x), x, a0);
        a1 = fmaf(bfhi(wv.x), x, a1);
        a2 = fmaf(bflo(wv.y), x, a2);
        a3 = fmaf(bfhi(wv.y), x, a3);
      }
      __syncthreads();
      SCR[tid * 4 + 0] = a0; SCR[tid * 4 + 1] = a1;
      SCR[tid * 4 + 2] = a2; SCR[tid * 4 + 3] = a3;
      __syncthreads();
      if (tid < 64){
        int g = tid >> 4, bb = tid & 15;
        float s = 0.f;
#pragma unroll
        for (int q = 0; q < 8; q++) s += SCR[q * 64 + bb * 4 + g];
        SCR[512 + g * 16 + bb] = s;
      }
      __syncthreads();
      if (tid < 16){
        float gi = SCR[512 + tid] + GBD[0];
        float gf = SCR[528 + tid] + GBD[1];
        float gg = SCR[544 + tid] + GBD[2];
        float go = SCR[560 + tid] + GBD[3];
        float cn = fsig(gf) * CDEC[tid] + fsig(gi) * ftanh(gg);
        CDEC[tid] = cn;
        float h = fsig(go) * ftanh(cn);
        XDw[(1536 + blk) * 16 + tid] = h;
      }
    }
    // (no barrier: stage1(t+1) touches only regions disjoint from stage3 readers;
    //  cross-step visibility provided by the next 1->2 barrier)
  }

  // ---- final barrier + projection for t = 299 (state parity 0) ----
  if (!gridbar(flags, abortf, ++bar, blk, tid, out)) return;
  if (blk >= 32 && blk < 48){
    const int b = blk - 32;
    const float* XD0 = XD;   // parity 0
    for (int i = tid; i < ARNN; i += NTHR) SCR[i] = XD0[(1536 + i) * 16 + b];
    __syncthreads();
    if (tid < 81){
      const float* wr = (tid < 80) ? P.prw + (size_t)tid * 1536 : P.gw;
      float s = (tid < 80) ? P.prb[tid] : P.gb[0];
      for (int k = 0; k < 1024; k++) s = fmaf(wr[k], SCR[k], s);
      for (int e = 0; e < 512; e++)  s = fmaf(wr[1024 + e], XD0[(1024 + e) * 16 + b], s);
      if (tid < 80) out[(size_t)(b * NMEL + tid) * T_DEC + (T_DEC - 1)] = s;
      else          out[OUT_GATE + (size_t)b * T_DEC + (T_DEC - 1)] = s;
    }
  }
}

// ---------------- launch ----------------
extern "C" void kernel_launch(void* const* d_in, const int* in_sizes, int n_in,
                              void* d_out, int out_size, void* d_ws, size_t ws_size,
                              hipStream_t stream){
  if (ws_size < (size_t)WS_END){
    hipLaunchKernelGGL(sentinel_kernel, dim3(1), dim3(64), 0, stream, (float*)d_out);
    return;
  }
  hipMemsetAsync(d_ws, 0, (size_t)WS_ZERO, stream);

  KParams P;
  P.memory = (const float*)d_in[0];  P.mels = (const float*)d_in[1];
  P.pw1 = (const float*)d_in[2];     P.pw2 = (const float*)d_in[3];
  P.mem_w = (const float*)d_in[4];   P.qw = (const float*)d_in[5];
  P.vw = (const float*)d_in[6];
  P.aih = (const float*)d_in[7];     P.ahh = (const float*)d_in[8];
  P.abi = (const float*)d_in[9];     P.abh = (const float*)d_in[10];
  P.dih = (const float*)d_in[11];    P.dhh = (const float*)d_in[12];
  P.dbi = (const float*)d_in[13];    P.dbh = (const float*)d_in[14];
  P.prw = (const float*)d_in[15];    P.prb = (const float*)d_in[16];
  P.gw = (const float*)d_in[17];     P.gb = (const float*)d_in[18];
  P.ws = (char*)d_ws; P.out = (float*)d_out;
  tf2x32(0u, 42u, 0u, 0u, P.k10, P.k11);
  tf2x32(0u, 42u, 0u, 1u, P.k20, P.k21);

  hipLaunchKernelGGL(decoder_kernel, dim3(NBLK), dim3(NTHR), 0, stream, P);
}